// Round 1
// baseline (351.671 us; speedup 1.0000x reference)
//
#include <hip/hip_runtime.h>
#include <hip/hip_bf16.h>

#define KNEIGH 16
#define FDIM   128

// One wave (64 lanes) per batch row. Each lane owns a float2 slice of the
// 128-float feature row: 8 B/lane * 64 lanes = 512 B per gathered row,
// a single fully-coalesced transaction per neighbor.
__global__ __launch_bounds__(256) void WeightedAggregator_89489938580183_kernel(
    const float* __restrict__ features,   // [N, 128]
    const float* __restrict__ neigh_w,    // [B, 16]
    const int*   __restrict__ neigh_idx,  // [B, 16] (int32 per harness)
    float*       __restrict__ out,        // [B, 128]
    int batch) {

    const int gtid = blockIdx.x * blockDim.x + threadIdx.x;
    const int row  = gtid >> 6;          // wave id = batch row
    const int lane = threadIdx.x & 63;
    if (row >= batch) return;

    // Lanes 0..15 hold the 16 (weight, index) pairs for this row.
    float wv = 0.0f;
    int   iv = 0;
    if (lane < KNEIGH) {
        wv = neigh_w[row * KNEIGH + lane];
        iv = neigh_idx[row * KNEIGH + lane];
    }

    // Sum of the 16 weights. XOR offsets 1,2,4,8 stay within the 16-lane
    // group; lanes >=16 contribute 0 and get 0 — broadcast from lane 0 after.
    float s = wv;
    s += __shfl_xor(s, 1);
    s += __shfl_xor(s, 2);
    s += __shfl_xor(s, 4);
    s += __shfl_xor(s, 8);
    const float inv = 1.0f / __shfl(s, 0);

    float2 acc = make_float2(0.0f, 0.0f);
    #pragma unroll
    for (int k = 0; k < KNEIGH; ++k) {
        const float wk = __shfl(wv, k) * inv;          // broadcast weight k
        const int   ik = __shfl(iv, k);                // broadcast index k
        const float2 f =
            ((const float2*)(features + (long long)ik * FDIM))[lane];
        acc.x = fmaf(wk, f.x, acc.x);
        acc.y = fmaf(wk, f.y, acc.y);
    }

    ((float2*)(out + (long long)row * FDIM))[lane] = acc;
}

extern "C" void kernel_launch(void* const* d_in, const int* in_sizes, int n_in,
                              void* d_out, int out_size, void* d_ws, size_t ws_size,
                              hipStream_t stream) {
    const float* features  = (const float*)d_in[0];
    const float* neigh_w   = (const float*)d_in[1];
    const int*   neigh_idx = (const int*)d_in[2];
    float*       out       = (float*)d_out;

    const int batch = in_sizes[1] / KNEIGH;      // 50000

    // 4 waves per 256-thread block, one wave per row.
    const int waves_per_block = 256 / 64;
    const int blocks = (batch + waves_per_block - 1) / waves_per_block;
    WeightedAggregator_89489938580183_kernel<<<blocks, 256, 0, stream>>>(
        features, neigh_w, neigh_idx, out, batch);
}